// Round 6
// baseline (381.351 us; speedup 1.0000x reference)
//
#include <hip/hip_runtime.h>
#include <stdint.h>

// SpatialGraphConv fused: 1x1 conv (192x64 GEMM) -> graph matmul (K=75) -> BN.
// B=64, C_in=64, T=300, V=25, K=3, C_out=64.  MFMA bf16 16x16x32, fp32 acc.
//
// v7: v6 main/norm2 UNCHANGED except the stats-atomic scheme.
//   Old: slot = bid & 63 -> 819K atomics on 512 cache lines (~1600 RMW/line,
//        suspected ~100us serialization floor in sgc_main).
//   New: 2048 slots, channel-major stats[c*2048 + slot], slot = bid & 2047
//        -> ~50 atomics/line (32x decontention).  finalize: 256-thread
//        vectorized reduce over the 1 MB stats array.

#define TT 3            // t per tile
#define NPIX (TT * 25)  // 75 pixels
#define NT1 5           // n-tiles (cols 75..79 pad)
#define NTILE 6400      // 64 b * 100 t-chunks
#define XSTRIDE 68      // xT row stride in floats
#define TSZ 4800        // shorts per output tile (64c * 75px)
#define NSLOT 2048      // stats slots (decontended atomics)

typedef short bf16x8 __attribute__((ext_vector_type(8)));
typedef float f32x4 __attribute__((ext_vector_type(4)));

union frag_u { bf16x8 v; uint32_t u[4]; };

__device__ inline short f2bf(float f) {
    union { float f; uint32_t u; } v; v.f = f;
    uint32_t u = v.u;
    u += 0x7fffu + ((u >> 16) & 1u);   // RNE
    return (short)(u >> 16);
}

__device__ inline uint32_t cvtpk(float lo, float hi) {
    uint32_t d;
    asm("v_cvt_pk_bf16_f32 %0, %1, %2" : "=v"(d) : "v"(lo), "v"(hi));
    return d;
}

__device__ inline short f2h(float f) {
    union { _Float16 h; short s; } u; u.h = (_Float16)f; return u.s;
}
__device__ inline float h2f(short s) {
    union { short s; _Float16 h; } u; u.s = s; return (float)u.h;
}

// ===========================================================================
// main (v4/v6 compute, decontended stats): one block per (b, 3-t tile)
// ===========================================================================
__global__ __launch_bounds__(256, 4) void sgc_main(
    const float* __restrict__ x, const float* __restrict__ W,
    const float* __restrict__ bias, const float* __restrict__ A,
    short* __restrict__ ws, float* __restrict__ stats_part)
{
    __shared__ __align__(16) short smem[18432];   // aliased views
    float* xT   = (float*)smem;   // [75][68] floats
    short* Ylds = smem;           // 4 waves * 9 tiles * 512 shorts

    const int tid  = threadIdx.x;
    const int lane = tid & 63;
    const int wave = tid >> 6;
    const int q4   = lane >> 4;
    const int wl   = lane & 15;
    const int bid  = blockIdx.x;
    const int b    = bid / 100;
    const int t0   = (bid % 100) * TT;

    bf16x8 wfrag[3][2];
    #pragma unroll
    for (int k = 0; k < 3; ++k) {
        int o = k * 64 + wave * 16 + wl;
        #pragma unroll
        for (int kb = 0; kb < 2; ++kb) {
            int ci0 = kb * 32 + q4 * 8;
            const float4 f0 = *(const float4*)&W[o * 64 + ci0];
            const float4 f1 = *(const float4*)&W[o * 64 + ci0 + 4];
            frag_u fr;
            fr.u[0] = cvtpk(f0.x, f0.y);
            fr.u[1] = cvtpk(f0.z, f0.w);
            fr.u[2] = cvtpk(f1.x, f1.y);
            fr.u[3] = cvtpk(f1.z, f1.w);
            wfrag[k][kb] = fr.v;
        }
    }

    {
        const float* xg = x + (size_t)b * 480000 + (size_t)t0 * 25 + lane * 7500;
        float4 vv[5];
        #pragma unroll
        for (int j = 0; j < 5; ++j) {
            int seg = wave + 4 * j;
            if (seg < 18) vv[j] = *(const float4*)(xg + seg * 4);
            else if (seg == 18) { vv[j].x = xg[72]; vv[j].y = xg[73]; vv[j].z = xg[74]; vv[j].w = 0.f; }
        }
        #pragma unroll
        for (int j = 0; j < 5; ++j) {
            int seg = wave + 4 * j;
            if (seg < 19) {
                int px0 = seg * 4;
                xT[(px0 + 0) * XSTRIDE + lane] = vv[j].x;
                xT[(px0 + 1) * XSTRIDE + lane] = vv[j].y;
                xT[(px0 + 2) * XSTRIDE + lane] = vv[j].z;
                if (seg < 18) xT[(px0 + 3) * XSTRIDE + lane] = vv[j].w;
            }
        }
    }
    __syncthreads();

    f32x4 acc[3][NT1];
    #pragma unroll
    for (int k = 0; k < 3; ++k)
        #pragma unroll
        for (int nt = 0; nt < NT1; ++nt) {
            f32x4 zf = {0.f, 0.f, 0.f, 0.f};
            acc[k][nt] = zf;
        }

    #pragma unroll
    for (int nt = 0; nt < NT1; ++nt) {
        int px = nt * 16 + wl;
        if (px > 74) px = 74;
        const float* row = &xT[px * XSTRIDE + q4 * 8];
        float4 a0 = *(const float4*)&row[0];
        float4 a1 = *(const float4*)&row[4];
        float4 a2 = *(const float4*)&row[32];
        float4 a3 = *(const float4*)&row[36];
        frag_u x0, x1;
        x0.u[0] = cvtpk(a0.x, a0.y); x0.u[1] = cvtpk(a0.z, a0.w);
        x0.u[2] = cvtpk(a1.x, a1.y); x0.u[3] = cvtpk(a1.z, a1.w);
        x1.u[0] = cvtpk(a2.x, a2.y); x1.u[1] = cvtpk(a2.z, a2.w);
        x1.u[2] = cvtpk(a3.x, a3.y); x1.u[3] = cvtpk(a3.z, a3.w);
        #pragma unroll
        for (int k = 0; k < 3; ++k) {
            acc[k][nt] = __builtin_amdgcn_mfma_f32_16x16x32_bf16(
                wfrag[k][0], x0.v, acc[k][nt], 0, 0, 0);
            acc[k][nt] = __builtin_amdgcn_mfma_f32_16x16x32_bf16(
                wfrag[k][1], x1.v, acc[k][nt], 0, 0, 0);
        }
    }
    __syncthreads();

    const int wbase = wave * 4608;
    #pragma unroll
    for (int tl = 0; tl < 9; ++tl)
        *(int*)&Ylds[wbase + tl * 512 + 384 + lane * 2] = 0;

    float4 bv[3];
    #pragma unroll
    for (int k = 0; k < 3; ++k)
        bv[k] = *(const float4*)&bias[k * 64 + wave * 16 + q4 * 4];

    #pragma unroll
    for (int nt = 0; nt < NT1; ++nt) {
        int n = nt * 16 + wl;
        if (n < NPIX) {
            int t = n / 25, v = n - t * 25;
            #pragma unroll
            for (int k = 0; k < 3; ++k) {
                int base = wbase + (t * 3 + k) * 512
                         + (v >> 3) * 128 + q4 * 32 + (v & 7);
                const float* bp = (const float*)&bv[k];
                #pragma unroll
                for (int r = 0; r < 4; ++r)
                    Ylds[base + r * 8] = f2bf(acc[k][nt][r] + bp[r]);
            }
        }
    }

    bf16x8 bfrag2[2][3];
    #pragma unroll
    for (int nt2 = 0; nt2 < 2; ++nt2) {
        int w = nt2 * 16 + wl;
        #pragma unroll
        for (int kb2 = 0; kb2 < 3; ++kb2) {
            frag_u fr;
            #pragma unroll
            for (int p = 0; p < 4; ++p) {
                int v0 = q4 * 8 + 2 * p;
                float a0 = (w < 25 && v0     < 25) ? A[(kb2 * 25 + v0) * 25 + w]     : 0.f;
                float a1 = (w < 25 && v0 + 1 < 25) ? A[(kb2 * 25 + v0 + 1) * 25 + w] : 0.f;
                fr.u[p] = cvtpk(a0, a1);
            }
            bfrag2[nt2][kb2] = fr.v;
        }
    }

    float ssum[4] = {0.f, 0.f, 0.f, 0.f};
    float ssq[4]  = {0.f, 0.f, 0.f, 0.f};
    short* wstile = ws + (size_t)bid * TSZ;
    const int c0  = wave * 16 + q4 * 4;

    #pragma unroll
    for (int t = 0; t < TT; ++t) {
        bf16x8 a2[3];
        #pragma unroll
        for (int kb2 = 0; kb2 < 3; ++kb2)
            a2[kb2] = *(const bf16x8*)&Ylds[wbase + (t * 3 + kb2) * 512 + lane * 8];

        f32x4 acc2[2];
        #pragma unroll
        for (int nt2 = 0; nt2 < 2; ++nt2) {
            f32x4 zf = {0.f, 0.f, 0.f, 0.f};
            acc2[nt2] = zf;
            #pragma unroll
            for (int kb2 = 0; kb2 < 3; ++kb2)
                acc2[nt2] = __builtin_amdgcn_mfma_f32_16x16x32_bf16(
                    a2[kb2], bfrag2[nt2][kb2], acc2[nt2], 0, 0, 0);
        }

        #pragma unroll
        for (int nt2 = 0; nt2 < 2; ++nt2) {
            int w = nt2 * 16 + wl;
            bool valid = (w < 25);
            #pragma unroll
            for (int r = 0; r < 4; ++r) {
                float val = acc2[nt2][r];
                if (valid) {
                    wstile[(c0 + r) * 75 + t * 25 + w] = f2h(val);
                    ssum[r] += val;
                    ssq[r]  += val * val;
                }
            }
        }
    }

    // ---- decontended stats: channel-major, 2048 slots (~50 atomics/line) ----
    #pragma unroll
    for (int r = 0; r < 4; ++r) {
        float s = ssum[r], q = ssq[r];
        #pragma unroll
        for (int d = 1; d < 16; d <<= 1) {
            s += __shfl_xor(s, d);
            q += __shfl_xor(q, d);
        }
        if (wl == 0) {
            int c = c0 + r;
            int slot = bid & (NSLOT - 1);
            atomicAdd(&stats_part[(size_t)c * NSLOT + slot], s);
            atomicAdd(&stats_part[(size_t)(64 + c) * NSLOT + slot], q);
        }
    }
}

// ---- finalize: 256 threads reduce stats[128][2048] -> scaleshift ----
__global__ void sgc_finalize(const float* __restrict__ stats_part,
                             const float* __restrict__ gamma,
                             const float* __restrict__ beta,
                             float* __restrict__ scaleshift)
{
    __shared__ float red[256];
    const int tid  = threadIdx.x;          // 256
    const int c    = tid & 127;
    const int half = tid >> 7;
    const float* p = stats_part + (size_t)c * NSLOT + half * (NSLOT / 2);
    float s = 0.f;
    #pragma unroll 4
    for (int j = 0; j < NSLOT / 8; ++j) {
        float4 v = *(const float4*)&p[j * 4];
        s += v.x + v.y + v.z + v.w;
    }
    red[tid] = s;
    __syncthreads();
    if (half == 0) red[c] = red[c] + red[c + 128];
    __syncthreads();
    if (tid < 64) {
        const float invN = 1.f / 480000.f;
        float mean = red[tid] * invN;
        float var  = red[64 + tid] * invN - mean * mean;
        float rstd = rsqrtf(var + 1e-5f);
        float sc = rstd * gamma[tid];
        scaleshift[tid]      = sc;
        scaleshift[64 + tid] = beta[tid] - mean * sc;
    }
}

// ===========================================================================
// norm2 (v6, unchanged): block = (b, 4-channel group); LDS-staged transpose,
// linear reads of ws, aligned float4 linear writes of out.
// ===========================================================================
__global__ __launch_bounds__(256, 4) void sgc_norm2(
    const short* __restrict__ ws, const float* __restrict__ scaleshift,
    float* __restrict__ out)
{
    __shared__ short lds_s[9600];     // 32 chunks * 4c * 75 shorts = 19200 B
    __shared__ float lds_ss[128];

    const int tid = threadIdx.x;
    const int bid = blockIdx.x;       // 1024 = 64 b * 16 cgroups
    const int b   = bid >> 4;
    const int cg  = bid & 15;

    if (tid < 128) lds_ss[tid] = scaleshift[tid];

    const uint32_t* wsu = (const uint32_t*)ws;
    const size_t tb = (size_t)b * 100;

    for (int s = 0; s < 4; ++s) {
        const int ch0 = s * 32;
        const int nch = (s < 3) ? 32 : 4;    // 100 = 3*32 + 4
        const int nu  = nch * 150;           // uints to stage

        __syncthreads();
        const int jmax = (nu + 255) >> 8;
        for (int j = 0, u = tid; j < jmax; ++j, u += 256) {
            if (u < nu) {
                int chl = u / 150;
                int off = u - chl * 150;
                ((uint32_t*)lds_s)[chl * 150 + off] =
                    wsu[(tb + ch0 + chl) * 2400 + cg * 150 + off];
            }
        }
        __syncthreads();

        const int per_c = nch * 75 / 4;      // 600 or 75 float4 per channel
        const int nslot = per_c * 4;
        const int jjmax = (nslot + 255) >> 8;
        for (int jj = 0, slot = tid; jj < jjmax; ++jj, slot += 256) {
            if (slot < nslot) {
                int cl  = slot / per_c;
                int f4i = slot - cl * per_c;
                int cgl = cg * 4 + cl;
                float sc = lds_ss[cgl], sh = lds_ss[64 + cgl];
                int p0 = f4i * 4;
                float4 v;
                #pragma unroll
                for (int k = 0; k < 4; ++k) {
                    int p   = p0 + k;
                    int chl = p / 75;
                    int idx = p - chl * 75;
                    ((float*)&v)[k] =
                        h2f(lds_s[chl * 300 + cl * 75 + idx]) * sc + sh;
                }
                *(float4*)&out[(size_t)(b * 64 + cgl) * 7500 + ch0 * 75 + p0] = v;
            }
        }
    }
}

// ===========================================================================
// Fallback (ws too small): direct fp32 out + in-place norm (v2 path)
// ===========================================================================
__global__ __launch_bounds__(256, 4) void sgc_main_fb(
    const float* __restrict__ x, const float* __restrict__ W,
    const float* __restrict__ bias, const float* __restrict__ A,
    float* __restrict__ out, float* __restrict__ stats_part)
{
    __shared__ __align__(16) short smem[18432];
    float* xT   = (float*)smem;
    short* Ylds = smem;

    const int tid  = threadIdx.x;
    const int lane = tid & 63;
    const int wave = tid >> 6;
    const int q4   = lane >> 4;
    const int wl   = lane & 15;
    const int bid  = blockIdx.x;
    const int b    = bid / 100;
    const int t0   = (bid % 100) * TT;

    bf16x8 wfrag[3][2];
    #pragma unroll
    for (int k = 0; k < 3; ++k) {
        int o = k * 64 + wave * 16 + wl;
        #pragma unroll
        for (int kb = 0; kb < 2; ++kb) {
            int ci0 = kb * 32 + q4 * 8;
            const float4 f0 = *(const float4*)&W[o * 64 + ci0];
            const float4 f1 = *(const float4*)&W[o * 64 + ci0 + 4];
            frag_u fr;
            fr.u[0] = cvtpk(f0.x, f0.y);
            fr.u[1] = cvtpk(f0.z, f0.w);
            fr.u[2] = cvtpk(f1.x, f1.y);
            fr.u[3] = cvtpk(f1.z, f1.w);
            wfrag[k][kb] = fr.v;
        }
    }

    {
        const float* xg = x + (size_t)b * 480000 + (size_t)t0 * 25 + lane * 7500;
        float4 vv[5];
        #pragma unroll
        for (int j = 0; j < 5; ++j) {
            int seg = wave + 4 * j;
            if (seg < 18) vv[j] = *(const float4*)(xg + seg * 4);
            else if (seg == 18) { vv[j].x = xg[72]; vv[j].y = xg[73]; vv[j].z = xg[74]; vv[j].w = 0.f; }
        }
        #pragma unroll
        for (int j = 0; j < 5; ++j) {
            int seg = wave + 4 * j;
            if (seg < 19) {
                int px0 = seg * 4;
                xT[(px0 + 0) * XSTRIDE + lane] = vv[j].x;
                xT[(px0 + 1) * XSTRIDE + lane] = vv[j].y;
                xT[(px0 + 2) * XSTRIDE + lane] = vv[j].z;
                if (seg < 18) xT[(px0 + 3) * XSTRIDE + lane] = vv[j].w;
            }
        }
    }
    __syncthreads();

    f32x4 acc[3][NT1];
    #pragma unroll
    for (int k = 0; k < 3; ++k)
        #pragma unroll
        for (int nt = 0; nt < NT1; ++nt) {
            f32x4 zf = {0.f, 0.f, 0.f, 0.f};
            acc[k][nt] = zf;
        }

    #pragma unroll
    for (int nt = 0; nt < NT1; ++nt) {
        int px = nt * 16 + wl;
        if (px > 74) px = 74;
        const float* row = &xT[px * XSTRIDE + q4 * 8];
        float4 a0 = *(const float4*)&row[0];
        float4 a1 = *(const float4*)&row[4];
        float4 a2 = *(const float4*)&row[32];
        float4 a3 = *(const float4*)&row[36];
        frag_u x0, x1;
        x0.u[0] = cvtpk(a0.x, a0.y); x0.u[1] = cvtpk(a0.z, a0.w);
        x0.u[2] = cvtpk(a1.x, a1.y); x0.u[3] = cvtpk(a1.z, a1.w);
        x1.u[0] = cvtpk(a2.x, a2.y); x1.u[1] = cvtpk(a2.z, a2.w);
        x1.u[2] = cvtpk(a3.x, a3.y); x1.u[3] = cvtpk(a3.z, a3.w);
        #pragma unroll
        for (int k = 0; k < 3; ++k) {
            acc[k][nt] = __builtin_amdgcn_mfma_f32_16x16x32_bf16(
                wfrag[k][0], x0.v, acc[k][nt], 0, 0, 0);
            acc[k][nt] = __builtin_amdgcn_mfma_f32_16x16x32_bf16(
                wfrag[k][1], x1.v, acc[k][nt], 0, 0, 0);
        }
    }
    __syncthreads();

    const int wbase = wave * 4608;
    #pragma unroll
    for (int tl = 0; tl < 9; ++tl)
        *(int*)&Ylds[wbase + tl * 512 + 384 + lane * 2] = 0;

    float4 bv[3];
    #pragma unroll
    for (int k = 0; k < 3; ++k)
        bv[k] = *(const float4*)&bias[k * 64 + wave * 16 + q4 * 4];

    #pragma unroll
    for (int nt = 0; nt < NT1; ++nt) {
        int n = nt * 16 + wl;
        if (n < NPIX) {
            int t = n / 25, v = n - t * 25;
            #pragma unroll
            for (int k = 0; k < 3; ++k) {
                int base = wbase + (t * 3 + k) * 512
                         + (v >> 3) * 128 + q4 * 32 + (v & 7);
                const float* bp = (const float*)&bv[k];
                #pragma unroll
                for (int r = 0; r < 4; ++r)
                    Ylds[base + r * 8] = f2bf(acc[k][nt][r] + bp[r]);
            }
        }
    }

    bf16x8 bfrag2[2][3];
    #pragma unroll
    for (int nt2 = 0; nt2 < 2; ++nt2) {
        int w = nt2 * 16 + wl;
        #pragma unroll
        for (int kb2 = 0; kb2 < 3; ++kb2) {
            frag_u fr;
            #pragma unroll
            for (int p = 0; p < 4; ++p) {
                int v0 = q4 * 8 + 2 * p;
                float a0 = (w < 25 && v0     < 25) ? A[(kb2 * 25 + v0) * 25 + w]     : 0.f;
                float a1 = (w < 25 && v0 + 1 < 25) ? A[(kb2 * 25 + v0 + 1) * 25 + w] : 0.f;
                fr.u[p] = cvtpk(a0, a1);
            }
            bfrag2[nt2][kb2] = fr.v;
        }
    }

    float ssum[4] = {0.f, 0.f, 0.f, 0.f};
    float ssq[4]  = {0.f, 0.f, 0.f, 0.f};
    const int c0  = wave * 16 + q4 * 4;

    #pragma unroll
    for (int t = 0; t < TT; ++t) {
        bf16x8 a2[3];
        #pragma unroll
        for (int kb2 = 0; kb2 < 3; ++kb2)
            a2[kb2] = *(const bf16x8*)&Ylds[wbase + (t * 3 + kb2) * 512 + lane * 8];

        f32x4 acc2[2];
        #pragma unroll
        for (int nt2 = 0; nt2 < 2; ++nt2) {
            f32x4 zf = {0.f, 0.f, 0.f, 0.f};
            acc2[nt2] = zf;
            #pragma unroll
            for (int kb2 = 0; kb2 < 3; ++kb2)
                acc2[nt2] = __builtin_amdgcn_mfma_f32_16x16x32_bf16(
                    a2[kb2], bfrag2[nt2][kb2], acc2[nt2], 0, 0, 0);
        }

        #pragma unroll
        for (int nt2 = 0; nt2 < 2; ++nt2) {
            int w = nt2 * 16 + wl;
            bool valid = (w < 25);
            #pragma unroll
            for (int r = 0; r < 4; ++r) {
                float val = acc2[nt2][r];
                if (valid) {
                    out[(size_t)((b * 64 + c0 + r) * 300 + t0 + t) * 25 + w] = val;
                    ssum[r] += val;
                    ssq[r]  += val * val;
                }
            }
        }
    }

    #pragma unroll
    for (int r = 0; r < 4; ++r) {
        float s = ssum[r], q = ssq[r];
        #pragma unroll
        for (int d = 1; d < 16; d <<= 1) {
            s += __shfl_xor(s, d);
            q += __shfl_xor(q, d);
        }
        if (wl == 0) {
            int c = c0 + r;
            int slot = bid & 63;
            atomicAdd(&stats_part[slot * 128 + c], s);
            atomicAdd(&stats_part[slot * 128 + 64 + c], q);
        }
    }
}

__global__ void sgc_finalize_fb(const float* __restrict__ stats_part,
                                const float* __restrict__ gamma,
                                const float* __restrict__ beta,
                                float* __restrict__ scaleshift)
{
    int c = threadIdx.x;  // 64 threads
    float s = 0.f, q = 0.f;
    #pragma unroll 8
    for (int slot = 0; slot < 64; ++slot) {
        s += stats_part[slot * 128 + c];
        q += stats_part[slot * 128 + 64 + c];
    }
    const float invN = 1.f / 480000.f;
    float mean = s * invN;
    float var  = q * invN - mean * mean;
    float rstd = rsqrtf(var + 1e-5f);
    float sc = rstd * gamma[c];
    scaleshift[c]      = sc;
    scaleshift[64 + c] = beta[c] - mean * sc;
}

__global__ __launch_bounds__(256) void sgc_norm_fb(float* __restrict__ out,
                                                   const float* __restrict__ scaleshift)
{
    const int total4 = 30720000 / 4;
    int stride = gridDim.x * 256;
    for (int i = blockIdx.x * 256 + threadIdx.x; i < total4; i += stride) {
        int c = (i / 1875) & 63;
        float sc = scaleshift[c], sh = scaleshift[64 + c];
        float4 v = *((float4*)out + i);
        v.x = v.x * sc + sh;
        v.y = v.y * sc + sh;
        v.z = v.z * sc + sh;
        v.w = v.w * sc + sh;
        *((float4*)out + i) = v;
    }
}

extern "C" void kernel_launch(void* const* d_in, const int* in_sizes, int n_in,
                              void* d_out, int out_size, void* d_ws, size_t ws_size,
                              hipStream_t stream)
{
    const float* x     = (const float*)d_in[0];
    const float* W     = (const float*)d_in[1];
    const float* bias  = (const float*)d_in[2];
    const float* A     = (const float*)d_in[3];
    const float* gamma = (const float*)d_in[4];
    const float* beta  = (const float*)d_in[5];
    float* out = (float*)d_out;

    const size_t tile_bytes = (size_t)NTILE * TSZ * sizeof(short);   // 61.44 MB
    const size_t stat_bytes = (size_t)128 * NSLOT * sizeof(float);   // 1 MB
    const size_t need = tile_bytes + stat_bytes + 128 * sizeof(float);

    if (ws_size >= need) {
        short* tiles      = (short*)d_ws;
        float* stats      = (float*)((char*)d_ws + tile_bytes);
        float* scaleshift = stats + 128 * NSLOT;

        hipMemsetAsync(stats, 0, stat_bytes, stream);
        sgc_main<<<NTILE, 256, 0, stream>>>(x, W, bias, A, tiles, stats);
        sgc_finalize<<<1, 256, 0, stream>>>(stats, gamma, beta, scaleshift);
        sgc_norm2<<<1024, 256, 0, stream>>>(tiles, scaleshift, out);
    } else {
        float* stats      = (float*)d_ws;
        float* scaleshift = stats + 64 * 128;

        hipMemsetAsync(stats, 0, 64 * 128 * sizeof(float), stream);
        sgc_main_fb<<<NTILE, 256, 0, stream>>>(x, W, bias, A, out, stats);
        sgc_finalize_fb<<<1, 64, 0, stream>>>(stats, gamma, beta, scaleshift);
        sgc_norm_fb<<<4096, 256, 0, stream>>>(out, scaleshift);
    }
}

// Round 7
// 293.225 us; speedup vs baseline: 1.3005x; 1.3005x over previous
//
#include <hip/hip_runtime.h>
#include <stdint.h>

// SpatialGraphConv fused: 1x1 conv (192x64 GEMM) -> graph matmul (K=75) -> BN.
// B=64, C_in=64, T=300, V=25, K=3, C_out=64.  MFMA bf16 16x16x32, fp32 acc.
//
// v8: v6 structure with EVERY global access in main coalesced.
//  - sgc_prep (one-time): converts W and A into fragment-ordered bf16 tables
//    in ws; main's wfrag/bfrag2 loads become coalesced dwordx4 (no gathers).
//  - x staging: flat-index coalesced dword loads (consecutive threads ->
//    consecutive px), 19-deep batched, transpose on the LDS write.
//  - stats scheme reverted to v6 (slot = bid & 63; v7's decontention hurt).
//  - norm2 / finalize / fallback: v6 unchanged.

#define TT 3            // t per tile
#define NPIX (TT * 25)  // 75 pixels
#define NT1 5           // n-tiles (cols 75..79 pad)
#define NTILE 6400      // 64 b * 100 t-chunks
#define XSTRIDE 68      // xT row stride in floats (272 B, 16B-aligned)
#define TSZ 4800        // shorts per output tile (64c * 75px)

typedef short bf16x8 __attribute__((ext_vector_type(8)));
typedef float f32x4 __attribute__((ext_vector_type(4)));

union frag_u { bf16x8 v; uint32_t u[4]; };

__device__ inline short f2bf(float f) {
    union { float f; uint32_t u; } v; v.f = f;
    uint32_t u = v.u;
    u += 0x7fffu + ((u >> 16) & 1u);   // RNE
    return (short)(u >> 16);
}

__device__ inline uint32_t cvtpk(float lo, float hi) {
    uint32_t d;
    asm("v_cvt_pk_bf16_f32 %0, %1, %2" : "=v"(d) : "v"(lo), "v"(hi));
    return d;
}

__device__ inline short f2h(float f) {
    union { _Float16 h; short s; } u; u.h = (_Float16)f; return u.s;
}
__device__ inline float h2f(short s) {
    union { short s; _Float16 h; } u; u.s = s; return (float)u.h;
}

// ===========================================================================
// prep: W -> wtab (fragment-linear bf16), A -> atab.  One block, one-time.
// wtab granule g = ((wave*3+k)*2+kb)*64 + lane : 8 bf16 of W row
// atab granule g = (nt2*3+kb2)*64 + lane       : 8 bf16 of A (padded)
// ===========================================================================
__global__ void sgc_prep(const float* __restrict__ W, const float* __restrict__ A,
                         short* __restrict__ wtab, short* __restrict__ atab)
{
    const int tid = threadIdx.x;   // 256
    #pragma unroll
    for (int i = 0; i < 6; ++i) {
        int g = tid + 256 * i;                 // 0..1535
        int lane = g & 63;
        int rest = g >> 6;                     // (wave*3+k)*2+kb, 0..23
        int kb   = rest & 1;
        int wk   = rest >> 1;                  // wave*3+k, 0..11
        int wave = wk / 3, k = wk - wave * 3;
        int o    = k * 64 + wave * 16 + (lane & 15);
        int ci0  = kb * 32 + (lane >> 4) * 8;
        const float* p = &W[o * 64 + ci0];
        frag_u fr;
        #pragma unroll
        for (int q = 0; q < 4; ++q)
            fr.u[q] = cvtpk(p[2 * q], p[2 * q + 1]);
        *(bf16x8*)&wtab[g * 8] = fr.v;
    }
    #pragma unroll
    for (int i = 0; i < 2; ++i) {
        int g = tid + 256 * i;                 // 0..383
        if (g < 384) {
            int lane = g & 63;
            int rest = g >> 6;                 // nt2*3+kb2, 0..5
            int nt2  = rest / 3, kb2 = rest - nt2 * 3;
            int w    = nt2 * 16 + (lane & 15);
            int v0   = (lane >> 4) * 8;
            frag_u fr;
            #pragma unroll
            for (int q = 0; q < 4; ++q) {
                int v = v0 + 2 * q;
                float a0 = (w < 25 && v     < 25) ? A[(kb2 * 25 + v) * 25 + w]     : 0.f;
                float a1 = (w < 25 && v + 1 < 25) ? A[(kb2 * 25 + v + 1) * 25 + w] : 0.f;
                fr.u[q] = cvtpk(a0, a1);
            }
            *(bf16x8*)&atab[g * 8] = fr.v;
        }
    }
}

// ===========================================================================
// main: one block per (b, 3-t tile) -> dense fp16 ws tile.  All coalesced.
// ===========================================================================
__global__ __launch_bounds__(256, 4) void sgc_main(
    const float* __restrict__ x, const short* __restrict__ wtab,
    const float* __restrict__ bias, const short* __restrict__ atab,
    short* __restrict__ ws, float* __restrict__ stats_part)
{
    __shared__ __align__(16) short smem[18432];   // aliased views
    float* xT   = (float*)smem;   // [75][68] floats
    short* Ylds = smem;           // 4 waves * 9 tiles * 512 shorts

    const int tid  = threadIdx.x;
    const int lane = tid & 63;
    const int wave = tid >> 6;
    const int q4   = lane >> 4;
    const int wl   = lane & 15;
    const int bid  = blockIdx.x;
    const int b    = bid / 100;
    const int t0   = (bid % 100) * TT;

    // ---- fragment loads: coalesced dwordx4 from prepped tables ----
    bf16x8 wfrag[3][2];
    #pragma unroll
    for (int k = 0; k < 3; ++k)
        #pragma unroll
        for (int kb = 0; kb < 2; ++kb)
            wfrag[k][kb] = *(const bf16x8*)
                &wtab[(((wave * 3 + k) * 2 + kb) * 64 + lane) * 8];

    bf16x8 bfrag2[2][3];
    #pragma unroll
    for (int nt2 = 0; nt2 < 2; ++nt2)
        #pragma unroll
        for (int kb2 = 0; kb2 < 3; ++kb2)
            bfrag2[nt2][kb2] = *(const bf16x8*)
                &atab[((nt2 * 3 + kb2) * 64 + lane) * 8];

    // ---- x staging: coalesced flat dword loads, batched, LDS transpose ----
    {
        const float* xsrc = x + (size_t)b * 480000 + (size_t)t0 * 25;
        float xv[19];
        #pragma unroll
        for (int j = 0; j < 19; ++j) {
            int f = tid + 256 * j;
            if (f < 4800) {
                int ci = f / 75;
                int px = f - ci * 75;
                xv[j] = xsrc[ci * 7500 + px];
            }
        }
        #pragma unroll
        for (int j = 0; j < 19; ++j) {
            int f = tid + 256 * j;
            if (f < 4800) {
                int ci = f / 75;
                int px = f - ci * 75;
                xT[px * XSTRIDE + ci] = xv[j];
            }
        }
    }
    __syncthreads();

    // ---- stage 1: Y(192x75) = W @ x ----
    f32x4 acc[3][NT1];
    #pragma unroll
    for (int k = 0; k < 3; ++k)
        #pragma unroll
        for (int nt = 0; nt < NT1; ++nt) {
            f32x4 zf = {0.f, 0.f, 0.f, 0.f};
            acc[k][nt] = zf;
        }

    #pragma unroll
    for (int nt = 0; nt < NT1; ++nt) {
        int px = nt * 16 + wl;
        if (px > 74) px = 74;
        const float* row = &xT[px * XSTRIDE + q4 * 8];
        float4 a0 = *(const float4*)&row[0];
        float4 a1 = *(const float4*)&row[4];
        float4 a2 = *(const float4*)&row[32];
        float4 a3 = *(const float4*)&row[36];
        frag_u x0, x1;
        x0.u[0] = cvtpk(a0.x, a0.y); x0.u[1] = cvtpk(a0.z, a0.w);
        x0.u[2] = cvtpk(a1.x, a1.y); x0.u[3] = cvtpk(a1.z, a1.w);
        x1.u[0] = cvtpk(a2.x, a2.y); x1.u[1] = cvtpk(a2.z, a2.w);
        x1.u[2] = cvtpk(a3.x, a3.y); x1.u[3] = cvtpk(a3.z, a3.w);
        #pragma unroll
        for (int k = 0; k < 3; ++k) {
            acc[k][nt] = __builtin_amdgcn_mfma_f32_16x16x32_bf16(
                wfrag[k][0], x0.v, acc[k][nt], 0, 0, 0);
            acc[k][nt] = __builtin_amdgcn_mfma_f32_16x16x32_bf16(
                wfrag[k][1], x1.v, acc[k][nt], 0, 0, 0);
        }
    }
    __syncthreads();   // xT reads done; region becomes Ylds

    const int wbase = wave * 4608;
    #pragma unroll
    for (int tl = 0; tl < 9; ++tl)
        *(int*)&Ylds[wbase + tl * 512 + 384 + lane * 2] = 0;

    float4 bv[3];
    #pragma unroll
    for (int k = 0; k < 3; ++k)
        bv[k] = *(const float4*)&bias[k * 64 + wave * 16 + q4 * 4];

    #pragma unroll
    for (int nt = 0; nt < NT1; ++nt) {
        int n = nt * 16 + wl;
        if (n < NPIX) {
            int t = n / 25, v = n - t * 25;
            #pragma unroll
            for (int k = 0; k < 3; ++k) {
                int base = wbase + (t * 3 + k) * 512
                         + (v >> 3) * 128 + q4 * 32 + (v & 7);
                const float* bp = (const float*)&bv[k];
                #pragma unroll
                for (int r = 0; r < 4; ++r)
                    Ylds[base + r * 8] = f2bf(acc[k][nt][r] + bp[r]);
            }
        }
    }

    // ---- stage 2 (wave-private Ylds) ----
    float ssum[4] = {0.f, 0.f, 0.f, 0.f};
    float ssq[4]  = {0.f, 0.f, 0.f, 0.f};
    short* wstile = ws + (size_t)bid * TSZ;
    const int c0  = wave * 16 + q4 * 4;

    #pragma unroll
    for (int t = 0; t < TT; ++t) {
        bf16x8 a2[3];
        #pragma unroll
        for (int kb2 = 0; kb2 < 3; ++kb2)
            a2[kb2] = *(const bf16x8*)&Ylds[wbase + (t * 3 + kb2) * 512 + lane * 8];

        f32x4 acc2[2];
        #pragma unroll
        for (int nt2 = 0; nt2 < 2; ++nt2) {
            f32x4 zf = {0.f, 0.f, 0.f, 0.f};
            acc2[nt2] = zf;
            #pragma unroll
            for (int kb2 = 0; kb2 < 3; ++kb2)
                acc2[nt2] = __builtin_amdgcn_mfma_f32_16x16x32_bf16(
                    a2[kb2], bfrag2[nt2][kb2], acc2[nt2], 0, 0, 0);
        }

        #pragma unroll
        for (int nt2 = 0; nt2 < 2; ++nt2) {
            int w = nt2 * 16 + wl;
            bool valid = (w < 25);
            #pragma unroll
            for (int r = 0; r < 4; ++r) {
                float val = acc2[nt2][r];
                if (valid) {
                    wstile[(c0 + r) * 75 + t * 25 + w] = f2h(val);
                    ssum[r] += val;
                    ssq[r]  += val * val;
                }
            }
        }
    }

    // ---- stats (v6 scheme) ----
    #pragma unroll
    for (int r = 0; r < 4; ++r) {
        float s = ssum[r], q = ssq[r];
        #pragma unroll
        for (int d = 1; d < 16; d <<= 1) {
            s += __shfl_xor(s, d);
            q += __shfl_xor(q, d);
        }
        if (wl == 0) {
            int c = c0 + r;
            int slot = bid & 63;
            atomicAdd(&stats_part[slot * 128 + c], s);
            atomicAdd(&stats_part[slot * 128 + 64 + c], q);
        }
    }
}

__global__ void sgc_finalize(const float* __restrict__ stats_part,
                             const float* __restrict__ gamma,
                             const float* __restrict__ beta,
                             float* __restrict__ scaleshift)
{
    int c = threadIdx.x;  // 64 threads
    float s = 0.f, q = 0.f;
    #pragma unroll 8
    for (int slot = 0; slot < 64; ++slot) {
        s += stats_part[slot * 128 + c];
        q += stats_part[slot * 128 + 64 + c];
    }
    const float invN = 1.f / 480000.f;
    float mean = s * invN;
    float var  = q * invN - mean * mean;
    float rstd = rsqrtf(var + 1e-5f);
    float sc = rstd * gamma[c];
    scaleshift[c]      = sc;
    scaleshift[64 + c] = beta[c] - mean * sc;
}

// ===========================================================================
// norm2 (v6, unchanged): block = (b, 4-channel group); LDS-staged transpose,
// linear reads of ws, aligned float4 linear writes of out.
// ===========================================================================
__global__ __launch_bounds__(256, 4) void sgc_norm2(
    const short* __restrict__ ws, const float* __restrict__ scaleshift,
    float* __restrict__ out)
{
    __shared__ short lds_s[9600];     // 32 chunks * 4c * 75 shorts = 19200 B
    __shared__ float lds_ss[128];

    const int tid = threadIdx.x;
    const int bid = blockIdx.x;       // 1024 = 64 b * 16 cgroups
    const int b   = bid >> 4;
    const int cg  = bid & 15;

    if (tid < 128) lds_ss[tid] = scaleshift[tid];

    const uint32_t* wsu = (const uint32_t*)ws;
    const size_t tb = (size_t)b * 100;

    for (int s = 0; s < 4; ++s) {
        const int ch0 = s * 32;
        const int nch = (s < 3) ? 32 : 4;    // 100 = 3*32 + 4
        const int nu  = nch * 150;           // uints to stage

        __syncthreads();
        const int jmax = (nu + 255) >> 8;
        for (int j = 0, u = tid; j < jmax; ++j, u += 256) {
            if (u < nu) {
                int chl = u / 150;
                int off = u - chl * 150;
                ((uint32_t*)lds_s)[chl * 150 + off] =
                    wsu[(tb + ch0 + chl) * 2400 + cg * 150 + off];
            }
        }
        __syncthreads();

        const int per_c = nch * 75 / 4;      // 600 or 75 float4 per channel
        const int nslot = per_c * 4;
        const int jjmax = (nslot + 255) >> 8;
        for (int jj = 0, slot = tid; jj < jjmax; ++jj, slot += 256) {
            if (slot < nslot) {
                int cl  = slot / per_c;
                int f4i = slot - cl * per_c;
                int cgl = cg * 4 + cl;
                float sc = lds_ss[cgl], sh = lds_ss[64 + cgl];
                int p0 = f4i * 4;
                float4 v;
                #pragma unroll
                for (int k = 0; k < 4; ++k) {
                    int p   = p0 + k;
                    int chl = p / 75;
                    int idx = p - chl * 75;
                    ((float*)&v)[k] =
                        h2f(lds_s[chl * 300 + cl * 75 + idx]) * sc + sh;
                }
                *(float4*)&out[(size_t)(b * 64 + cgl) * 7500 + ch0 * 75 + p0] = v;
            }
        }
    }
}

// ===========================================================================
// Fallback (ws too small): v6 fallback unchanged (uses W/A directly)
// ===========================================================================
__global__ __launch_bounds__(256, 4) void sgc_main_fb(
    const float* __restrict__ x, const float* __restrict__ W,
    const float* __restrict__ bias, const float* __restrict__ A,
    float* __restrict__ out, float* __restrict__ stats_part)
{
    __shared__ __align__(16) short smem[18432];
    float* xT   = (float*)smem;
    short* Ylds = smem;

    const int tid  = threadIdx.x;
    const int lane = tid & 63;
    const int wave = tid >> 6;
    const int q4   = lane >> 4;
    const int wl   = lane & 15;
    const int bid  = blockIdx.x;
    const int b    = bid / 100;
    const int t0   = (bid % 100) * TT;

    bf16x8 wfrag[3][2];
    #pragma unroll
    for (int k = 0; k < 3; ++k) {
        int o = k * 64 + wave * 16 + wl;
        #pragma unroll
        for (int kb = 0; kb < 2; ++kb) {
            int ci0 = kb * 32 + q4 * 8;
            const float4 f0 = *(const float4*)&W[o * 64 + ci0];
            const float4 f1 = *(const float4*)&W[o * 64 + ci0 + 4];
            frag_u fr;
            fr.u[0] = cvtpk(f0.x, f0.y);
            fr.u[1] = cvtpk(f0.z, f0.w);
            fr.u[2] = cvtpk(f1.x, f1.y);
            fr.u[3] = cvtpk(f1.z, f1.w);
            wfrag[k][kb] = fr.v;
        }
    }

    {
        const float* xg = x + (size_t)b * 480000 + (size_t)t0 * 25 + lane * 7500;
        float4 vv[5];
        #pragma unroll
        for (int j = 0; j < 5; ++j) {
            int seg = wave + 4 * j;
            if (seg < 18) vv[j] = *(const float4*)(xg + seg * 4);
            else if (seg == 18) { vv[j].x = xg[72]; vv[j].y = xg[73]; vv[j].z = xg[74]; vv[j].w = 0.f; }
        }
        #pragma unroll
        for (int j = 0; j < 5; ++j) {
            int seg = wave + 4 * j;
            if (seg < 19) {
                int px0 = seg * 4;
                xT[(px0 + 0) * XSTRIDE + lane] = vv[j].x;
                xT[(px0 + 1) * XSTRIDE + lane] = vv[j].y;
                xT[(px0 + 2) * XSTRIDE + lane] = vv[j].z;
                if (seg < 18) xT[(px0 + 3) * XSTRIDE + lane] = vv[j].w;
            }
        }
    }
    __syncthreads();

    f32x4 acc[3][NT1];
    #pragma unroll
    for (int k = 0; k < 3; ++k)
        #pragma unroll
        for (int nt = 0; nt < NT1; ++nt) {
            f32x4 zf = {0.f, 0.f, 0.f, 0.f};
            acc[k][nt] = zf;
        }

    #pragma unroll
    for (int nt = 0; nt < NT1; ++nt) {
        int px = nt * 16 + wl;
        if (px > 74) px = 74;
        const float* row = &xT[px * XSTRIDE + q4 * 8];
        float4 a0 = *(const float4*)&row[0];
        float4 a1 = *(const float4*)&row[4];
        float4 a2 = *(const float4*)&row[32];
        float4 a3 = *(const float4*)&row[36];
        frag_u x0, x1;
        x0.u[0] = cvtpk(a0.x, a0.y); x0.u[1] = cvtpk(a0.z, a0.w);
        x0.u[2] = cvtpk(a1.x, a1.y); x0.u[3] = cvtpk(a1.z, a1.w);
        x1.u[0] = cvtpk(a2.x, a2.y); x1.u[1] = cvtpk(a2.z, a2.w);
        x1.u[2] = cvtpk(a3.x, a3.y); x1.u[3] = cvtpk(a3.z, a3.w);
        #pragma unroll
        for (int k = 0; k < 3; ++k) {
            acc[k][nt] = __builtin_amdgcn_mfma_f32_16x16x32_bf16(
                wfrag[k][0], x0.v, acc[k][nt], 0, 0, 0);
            acc[k][nt] = __builtin_amdgcn_mfma_f32_16x16x32_bf16(
                wfrag[k][1], x1.v, acc[k][nt], 0, 0, 0);
        }
    }
    __syncthreads();

    const int wbase = wave * 4608;
    #pragma unroll
    for (int tl = 0; tl < 9; ++tl)
        *(int*)&Ylds[wbase + tl * 512 + 384 + lane * 2] = 0;

    float4 bv[3];
    #pragma unroll
    for (int k = 0; k < 3; ++k)
        bv[k] = *(const float4*)&bias[k * 64 + wave * 16 + q4 * 4];

    #pragma unroll
    for (int nt = 0; nt < NT1; ++nt) {
        int n = nt * 16 + wl;
        if (n < NPIX) {
            int t = n / 25, v = n - t * 25;
            #pragma unroll
            for (int k = 0; k < 3; ++k) {
                int base = wbase + (t * 3 + k) * 512
                         + (v >> 3) * 128 + q4 * 32 + (v & 7);
                const float* bp = (const float*)&bv[k];
                #pragma unroll
                for (int r = 0; r < 4; ++r)
                    Ylds[base + r * 8] = f2bf(acc[k][nt][r] + bp[r]);
            }
        }
    }

    bf16x8 bfrag2[2][3];
    #pragma unroll
    for (int nt2 = 0; nt2 < 2; ++nt2) {
        int w = nt2 * 16 + wl;
        #pragma unroll
        for (int kb2 = 0; kb2 < 3; ++kb2) {
            frag_u fr;
            #pragma unroll
            for (int p = 0; p < 4; ++p) {
                int v0 = q4 * 8 + 2 * p;
                float a0 = (w < 25 && v0     < 25) ? A[(kb2 * 25 + v0) * 25 + w]     : 0.f;
                float a1 = (w < 25 && v0 + 1 < 25) ? A[(kb2 * 25 + v0 + 1) * 25 + w] : 0.f;
                fr.u[p] = cvtpk(a0, a1);
            }
            bfrag2[nt2][kb2] = fr.v;
        }
    }

    float ssum[4] = {0.f, 0.f, 0.f, 0.f};
    float ssq[4]  = {0.f, 0.f, 0.f, 0.f};
    const int c0  = wave * 16 + q4 * 4;

    #pragma unroll
    for (int t = 0; t < TT; ++t) {
        bf16x8 a2[3];
        #pragma unroll
        for (int kb2 = 0; kb2 < 3; ++kb2)
            a2[kb2] = *(const bf16x8*)&Ylds[wbase + (t * 3 + kb2) * 512 + lane * 8];

        f32x4 acc2[2];
        #pragma unroll
        for (int nt2 = 0; nt2 < 2; ++nt2) {
            f32x4 zf = {0.f, 0.f, 0.f, 0.f};
            acc2[nt2] = zf;
            #pragma unroll
            for (int kb2 = 0; kb2 < 3; ++kb2)
                acc2[nt2] = __builtin_amdgcn_mfma_f32_16x16x32_bf16(
                    a2[kb2], bfrag2[nt2][kb2], acc2[nt2], 0, 0, 0);
        }

        #pragma unroll
        for (int nt2 = 0; nt2 < 2; ++nt2) {
            int w = nt2 * 16 + wl;
            bool valid = (w < 25);
            #pragma unroll
            for (int r = 0; r < 4; ++r) {
                float val = acc2[nt2][r];
                if (valid) {
                    out[(size_t)((b * 64 + c0 + r) * 300 + t0 + t) * 25 + w] = val;
                    ssum[r] += val;
                    ssq[r]  += val * val;
                }
            }
        }
    }

    #pragma unroll
    for (int r = 0; r < 4; ++r) {
        float s = ssum[r], q = ssq[r];
        #pragma unroll
        for (int d = 1; d < 16; d <<= 1) {
            s += __shfl_xor(s, d);
            q += __shfl_xor(q, d);
        }
        if (wl == 0) {
            int c = c0 + r;
            int slot = bid & 63;
            atomicAdd(&stats_part[slot * 128 + c], s);
            atomicAdd(&stats_part[slot * 128 + 64 + c], q);
        }
    }
}

__global__ __launch_bounds__(256) void sgc_norm_fb(float* __restrict__ out,
                                                   const float* __restrict__ scaleshift)
{
    const int total4 = 30720000 / 4;
    int stride = gridDim.x * 256;
    for (int i = blockIdx.x * 256 + threadIdx.x; i < total4; i += stride) {
        int c = (i / 1875) & 63;
        float sc = scaleshift[c], sh = scaleshift[64 + c];
        float4 v = *((float4*)out + i);
        v.x = v.x * sc + sh;
        v.y = v.y * sc + sh;
        v.z = v.z * sc + sh;
        v.w = v.w * sc + sh;
        *((float4*)out + i) = v;
    }
}

extern "C" void kernel_launch(void* const* d_in, const int* in_sizes, int n_in,
                              void* d_out, int out_size, void* d_ws, size_t ws_size,
                              hipStream_t stream)
{
    const float* x     = (const float*)d_in[0];
    const float* W     = (const float*)d_in[1];
    const float* bias  = (const float*)d_in[2];
    const float* A     = (const float*)d_in[3];
    const float* gamma = (const float*)d_in[4];
    const float* beta  = (const float*)d_in[5];
    float* out = (float*)d_out;

    const size_t tile_bytes = (size_t)NTILE * TSZ * sizeof(short);   // 61.44 MB
    const size_t stat_bytes = 64 * 128 * sizeof(float);              // 32 KB
    const size_t ss_bytes   = 128 * sizeof(float);
    const size_t wtab_bytes = 1536 * 8 * sizeof(short);              // 24 KB
    const size_t atab_bytes = 384 * 8 * sizeof(short);               // 6 KB
    const size_t need = tile_bytes + stat_bytes + ss_bytes + wtab_bytes + atab_bytes;

    if (ws_size >= need) {
        char* base        = (char*)d_ws;
        short* tiles      = (short*)base;
        float* stats      = (float*)(base + tile_bytes);
        float* scaleshift = (float*)(base + tile_bytes + stat_bytes);
        short* wtab       = (short*)(base + tile_bytes + stat_bytes + ss_bytes);
        short* atab       = (short*)(base + tile_bytes + stat_bytes + ss_bytes + wtab_bytes);

        sgc_prep<<<1, 256, 0, stream>>>(W, A, wtab, atab);
        hipMemsetAsync(stats, 0, stat_bytes, stream);
        sgc_main<<<NTILE, 256, 0, stream>>>(x, wtab, bias, atab, tiles, stats);
        sgc_finalize<<<1, 64, 0, stream>>>(stats, gamma, beta, scaleshift);
        sgc_norm2<<<1024, 256, 0, stream>>>(tiles, scaleshift, out);
    } else {
        float* stats      = (float*)d_ws;
        float* scaleshift = stats + 64 * 128;

        hipMemsetAsync(stats, 0, 64 * 128 * sizeof(float), stream);
        sgc_main_fb<<<NTILE, 256, 0, stream>>>(x, W, bias, A, out, stats);
        sgc_finalize<<<1, 64, 0, stream>>>(stats, gamma, beta, scaleshift);
        sgc_norm_fb<<<4096, 256, 0, stream>>>(out, scaleshift);
    }
}